// Round 1
// baseline (5199.984 us; speedup 1.0000x reference)
//
#include <hip/hip_runtime.h>
#include <math.h>

#define B_T   128
#define NS    128
#define NQ    512
#define DIN   256
#define DOUT  64

#define MU_SIZE  (B_T*NQ*DOUT)            // 4,194,304 floats
#define SIG_SIZE (B_T*NQ*DOUT*DOUT)       // 268,435,456 floats
#define NLL_IDX  (MU_SIZE + SIG_SIZE)     // 272,629,760

// XOR/rotate swizzle for the fp32 spread workspace (exactly 64 KB, conflict-free)
#define WIDX(i,q) ((i)*64 + (((q)+(i)) & 63))

// ---------------------------------------------------------------------------
// K0a: Sp = A @ A^T  (fp64 accumulate), alpha = 1
// ---------------------------------------------------------------------------
__global__ __launch_bounds__(256) void k_prior_sp(const float* __restrict__ A,
                                                  double* __restrict__ Sp) {
    __shared__ float Ai[16][260];
    __shared__ float Aj[16][260];
    int bi = blockIdx.x;
    int i0 = (bi >> 4) << 4;
    int j0 = (bi & 15) << 4;
    int tid = threadIdx.x;
    for (int idx = tid; idx < 16 * 256; idx += 256) {
        int r = idx >> 8, c = idx & 255;
        Ai[r][c] = A[(i0 + r) * 256 + c];
        Aj[r][c] = A[(j0 + r) * 256 + c];
    }
    __syncthreads();
    int r = tid >> 4, c = tid & 15;
    double acc = 0.0;
    for (int k = 0; k < 256; ++k)
        acc += (double)Ai[r][k] * (double)Aj[c][k];
    Sp[(i0 + r) * 256 + (j0 + c)] = acc;
}

// ---------------------------------------------------------------------------
// K0b: MPN = Sp @ m_prior
// ---------------------------------------------------------------------------
__global__ __launch_bounds__(64) void k_prior_mpn(const double* __restrict__ Sp,
                                                  const float* __restrict__ MP,
                                                  double* __restrict__ MPN) {
    int i = blockIdx.x, k = threadIdx.x;
    double acc = 0.0;
    for (int t = 0; t < 256; ++t)
        acc += Sp[i * 256 + t] * (double)MP[t * 64 + k];
    MPN[i * 64 + k] = acc;
}

// ---------------------------------------------------------------------------
// K1: G_b = Phi_s^T Phi_s + Sp   (lower-triangle 64x64 tiles only, fp64)
// ---------------------------------------------------------------------------
__global__ __launch_bounds__(256) void k_build_G(const float* __restrict__ PHI,
                                                 const double* __restrict__ Sp,
                                                 double* __restrict__ G) {
    __shared__ float As[128][64];
    __shared__ float Bs[128][64];
    int b = blockIdx.x;
    int by = blockIdx.y;
    int ti = 0;
    while (((ti + 1) * (ti + 2)) / 2 <= by) ti++;
    int tj = by - (ti * (ti + 1)) / 2;
    int i0 = ti * 64, j0 = tj * 64;
    int tid = threadIdx.x;
    const float* Pb = PHI + b * (NS * DIN);
    for (int idx = tid; idx < 128 * 64; idx += 256) {
        int n = idx >> 6, c = idx & 63;
        As[n][c] = Pb[n * 256 + i0 + c];
        Bs[n][c] = Pb[n * 256 + j0 + c];
    }
    __syncthreads();
    int tx = tid & 15, ty = tid >> 4;
    double acc[4][4];
#pragma unroll
    for (int r = 0; r < 4; ++r)
#pragma unroll
        for (int s = 0; s < 4; ++s) acc[r][s] = 0.0;
    for (int n = 0; n < 128; ++n) {
        float a0 = As[n][4 * ty + 0], a1 = As[n][4 * ty + 1];
        float a2 = As[n][4 * ty + 2], a3 = As[n][4 * ty + 3];
        float b0 = Bs[n][4 * tx + 0], b1 = Bs[n][4 * tx + 1];
        float b2 = Bs[n][4 * tx + 2], b3 = Bs[n][4 * tx + 3];
        acc[0][0] += (double)a0 * b0; acc[0][1] += (double)a0 * b1;
        acc[0][2] += (double)a0 * b2; acc[0][3] += (double)a0 * b3;
        acc[1][0] += (double)a1 * b0; acc[1][1] += (double)a1 * b1;
        acc[1][2] += (double)a1 * b2; acc[1][3] += (double)a1 * b3;
        acc[2][0] += (double)a2 * b0; acc[2][1] += (double)a2 * b1;
        acc[2][2] += (double)a2 * b2; acc[2][3] += (double)a2 * b3;
        acc[3][0] += (double)a3 * b0; acc[3][1] += (double)a3 * b1;
        acc[3][2] += (double)a3 * b2; acc[3][3] += (double)a3 * b3;
    }
    double* Gb = G + b * 65536;
#pragma unroll
    for (int r = 0; r < 4; ++r) {
        int i = i0 + 4 * ty + r;
#pragma unroll
        for (int s = 0; s < 4; ++s) {
            int j = j0 + 4 * tx + s;
            Gb[i * 256 + j] = acc[r][s] + Sp[i * 256 + j];
        }
    }
}

// ---------------------------------------------------------------------------
// K2: RHS_b = Phi_s^T Y_s + MPN  (fp64)
// ---------------------------------------------------------------------------
__global__ __launch_bounds__(256) void k_build_rhs(const float* __restrict__ PHI,
                                                   const float* __restrict__ Y,
                                                   const double* __restrict__ MPN,
                                                   double* __restrict__ RHS) {
    __shared__ float As[128][64];
    __shared__ float Ys[128][64];
    int b = blockIdx.x, i0 = blockIdx.y * 64, tid = threadIdx.x;
    const float* Pb = PHI + b * (NS * DIN);
    const float* Yb = Y + b * (NS * DOUT);
    for (int idx = tid; idx < 128 * 64; idx += 256) {
        int n = idx >> 6, c = idx & 63;
        As[n][c] = Pb[n * 256 + i0 + c];
        Ys[n][c] = Yb[n * 64 + c];
    }
    __syncthreads();
    int tx = tid & 15, ty = tid >> 4;
    double acc[4][4];
#pragma unroll
    for (int r = 0; r < 4; ++r)
#pragma unroll
        for (int s = 0; s < 4; ++s) acc[r][s] = 0.0;
    for (int n = 0; n < 128; ++n) {
        float a0 = As[n][4 * ty + 0], a1 = As[n][4 * ty + 1];
        float a2 = As[n][4 * ty + 2], a3 = As[n][4 * ty + 3];
        float y0 = Ys[n][4 * tx + 0], y1 = Ys[n][4 * tx + 1];
        float y2 = Ys[n][4 * tx + 2], y3 = Ys[n][4 * tx + 3];
        acc[0][0] += (double)a0 * y0; acc[0][1] += (double)a0 * y1;
        acc[0][2] += (double)a0 * y2; acc[0][3] += (double)a0 * y3;
        acc[1][0] += (double)a1 * y0; acc[1][1] += (double)a1 * y1;
        acc[1][2] += (double)a1 * y2; acc[1][3] += (double)a1 * y3;
        acc[2][0] += (double)a2 * y0; acc[2][1] += (double)a2 * y1;
        acc[2][2] += (double)a2 * y2; acc[2][3] += (double)a2 * y3;
        acc[3][0] += (double)a3 * y0; acc[3][1] += (double)a3 * y1;
        acc[3][2] += (double)a3 * y2; acc[3][3] += (double)a3 * y3;
    }
    double* Rb = RHS + b * 16384;
#pragma unroll
    for (int r = 0; r < 4; ++r) {
        int i = i0 + 4 * ty + r;
#pragma unroll
        for (int s = 0; s < 4; ++s) {
            int kc = 4 * tx + s;
            Rb[i * 64 + kc] = acc[r][s] + MPN[i * 64 + kc];
        }
    }
}

// ---------------------------------------------------------------------------
// K3: blocked Cholesky (NB=8) of G_b (lower, fp64), in-place.
//     Writes transposed factor LT[k*256+i] = L[i][k] (i>=k) and INVD[k]=1/L[k][k].
// ---------------------------------------------------------------------------
__global__ __launch_bounds__(256) void k_chol(double* __restrict__ G,
                                              double* __restrict__ LT,
                                              double* __restrict__ INVD) {
    __shared__ double P[8][256];
    int b = blockIdx.x, tid = threadIdx.x;
    double* Gb = G + b * 65536;
    double* LTb = LT + b * 65536;
    for (int k0 = 0; k0 < 256; k0 += 8) {
        // stage 8 columns (each thread reads one row's 8 consecutive doubles)
#pragma unroll
        for (int p = 0; p < 8; ++p) P[p][tid] = Gb[tid * 256 + k0 + p];
        __syncthreads();
        // factor panel
        for (int p = 0; p < 8; ++p) {
            int k = k0 + p;
            if (tid >= k) {
                double v = P[p][tid];
                for (int p2 = 0; p2 < p; ++p2) v -= P[p2][tid] * P[p2][k];
                P[p][tid] = v;
            }
            __syncthreads();
            double d = sqrt(fmax(P[p][k], 1e-300));
            double inv = 1.0 / d;
            if (tid > k) P[p][tid] *= inv;
            else if (tid == k) { P[p][tid] = d; INVD[b * 256 + k] = inv; }
            __syncthreads();
        }
        // write finished panel to LT (coalesced rows)
#pragma unroll
        for (int p = 0; p < 8; ++p) {
            int k = k0 + p;
            if (tid >= k) LTb[k * 256 + tid] = P[p][tid];
        }
        // trailing update (lower triangle, i,j >= k0+8)
        int ty = tid >> 4, tx = tid & 15;
        for (int i = k0 + 8 + ty; i < 256; i += 16) {
            double pi[8];
#pragma unroll
            for (int p = 0; p < 8; ++p) pi[p] = P[p][i];
            for (int j = k0 + 8 + tx; j <= i; j += 16) {
                double g = Gb[i * 256 + j];
#pragma unroll
                for (int p = 0; p < 8; ++p) g -= pi[p] * P[p][j];
                Gb[i * 256 + j] = g;
            }
        }
        __syncthreads();
    }
}

// ---------------------------------------------------------------------------
// K4: solve G m = RHS via L L^T (fp64), 32 RHS columns per block, in-place.
// ---------------------------------------------------------------------------
__global__ __launch_bounds__(256) void k_solve_m(const double* __restrict__ LT,
                                                 const double* __restrict__ INVD,
                                                 double* __restrict__ RHS) {
    __shared__ double Z[256 * 32];   // exactly 64 KB
    int b = blockIdx.x, c0 = blockIdx.y * 32, tid = threadIdx.x;
    const double* LTb = LT + b * 65536;
    const double* invd = INVD + b * 256;
    double* Rb = RHS + b * 16384;
    for (int idx = tid; idx < 8192; idx += 256) {
        int i = idx >> 5, c = idx & 31;
        Z[idx] = Rb[i * 64 + c0 + c];
    }
    __syncthreads();
    int q = tid & 31, grp = tid >> 5;
    // forward: L z = rhs  (column-oriented)
    for (int k = 0; k < 256; ++k) {
        if (tid < 32) Z[k * 32 + q] *= invd[k];
        __syncthreads();
        double w = Z[k * 32 + q];
        for (int i = k + 1 + grp; i < 256; i += 8)
            Z[i * 32 + q] -= LTb[k * 256 + i] * w;
        __syncthreads();
    }
    // backward: L^T m = z  (axpy form; L[k][i] = LT[i*256+k] for i<k)
    for (int k = 255; k >= 0; --k) {
        if (tid < 32) Z[k * 32 + q] *= invd[k];
        __syncthreads();
        double x = Z[k * 32 + q];
        for (int i = grp; i < k; i += 8)
            Z[i * 32 + q] -= LTb[i * 256 + k] * x;
        __syncthreads();
    }
    for (int idx = tid; idx < 8192; idx += 256) {
        int i = idx >> 5, c = idx & 31;
        Rb[i * 64 + c0 + c] = Z[idx];
    }
}

// ---------------------------------------------------------------------------
// K5: spread_fac = 1 + ||L^{-1} phi_q||^2  (fp32 solve, 64 queries per block)
// ---------------------------------------------------------------------------
__global__ __launch_bounds__(256) void k_spread(const float* __restrict__ PHIQ,
                                                const double* __restrict__ LT,
                                                const double* __restrict__ INVD,
                                                float* __restrict__ SPREAD) {
    __shared__ float W[256 * 64];    // exactly 64 KB, rotate-swizzled
    int b = blockIdx.x, q0 = blockIdx.y * 64, tid = threadIdx.x;
    const double* LTb = LT + b * 65536;
    const double* invd = INVD + b * 256;
    const float* Qb = PHIQ + b * (NQ * DIN) + q0 * DIN;
    for (int it = 0; it < 64; ++it)
        W[WIDX(tid, it)] = Qb[it * 256 + tid];
    __syncthreads();
    int q = tid & 63, grp = tid >> 6;
    for (int k = 0; k < 256; ++k) {
        if (grp == 0) W[WIDX(k, q)] *= (float)invd[k];
        __syncthreads();
        float w = W[WIDX(k, q)];
        for (int i = k + 1 + grp; i < 256; i += 4)
            W[WIDX(i, q)] -= (float)LTb[k * 256 + i] * w;
        __syncthreads();
    }
    if (tid < 64) {
        float ss = 0.0f;
        for (int i = 0; i < 256; ++i) {
            float v = W[WIDX(i, tid)];
            ss += v * v;
        }
        SPREAD[b * 512 + q0 + tid] = 1.0f + ss;
    }
}

// ---------------------------------------------------------------------------
// K6: mu = Phi_q @ m  (fp32 GEMM, m cast from fp64)
// ---------------------------------------------------------------------------
__global__ __launch_bounds__(256) void k_mu(const float* __restrict__ PHIQ,
                                            const double* __restrict__ M,
                                            float* __restrict__ MU) {
    __shared__ float Qs[64][65];
    __shared__ float Ms[64][64];
    int b = blockIdx.x, q0 = blockIdx.y * 64, tid = threadIdx.x;
    int tx = tid & 15, ty = tid >> 4;
    const float* Qb = PHIQ + b * (NQ * DIN) + q0 * DIN;
    const double* Mb = M + b * 16384;
    float acc[4][4];
#pragma unroll
    for (int r = 0; r < 4; ++r)
#pragma unroll
        for (int s = 0; s < 4; ++s) acc[r][s] = 0.0f;
    for (int c0 = 0; c0 < 256; c0 += 64) {
        for (int idx = tid; idx < 4096; idx += 256) {
            int r = idx >> 6, c = idx & 63;
            Qs[r][c] = Qb[r * 256 + c0 + c];
            Ms[r][c] = (float)Mb[(c0 + r) * 64 + c];
        }
        __syncthreads();
        for (int kk = 0; kk < 64; ++kk) {
            float a0 = Qs[4 * ty + 0][kk], a1 = Qs[4 * ty + 1][kk];
            float a2 = Qs[4 * ty + 2][kk], a3 = Qs[4 * ty + 3][kk];
            float b0 = Ms[kk][4 * tx + 0], b1 = Ms[kk][4 * tx + 1];
            float b2 = Ms[kk][4 * tx + 2], b3 = Ms[kk][4 * tx + 3];
            acc[0][0] += a0 * b0; acc[0][1] += a0 * b1; acc[0][2] += a0 * b2; acc[0][3] += a0 * b3;
            acc[1][0] += a1 * b0; acc[1][1] += a1 * b1; acc[1][2] += a1 * b2; acc[1][3] += a1 * b3;
            acc[2][0] += a2 * b0; acc[2][1] += a2 * b1; acc[2][2] += a2 * b2; acc[2][3] += a2 * b3;
            acc[3][0] += a3 * b0; acc[3][1] += a3 * b1; acc[3][2] += a3 * b2; acc[3][3] += a3 * b3;
        }
        __syncthreads();
    }
#pragma unroll
    for (int r = 0; r < 4; ++r) {
        float4 v = make_float4(acc[r][0], acc[r][1], acc[r][2], acc[r][3]);
        *(float4*)&MU[(b * NQ + q0 + 4 * ty + r) * 64 + 4 * tx] = v;
    }
}

// ---------------------------------------------------------------------------
// K8: nll partial sums per 256-element block of (b,q)
// ---------------------------------------------------------------------------
__global__ __launch_bounds__(256) void k_nll_part(const float* __restrict__ YQ,
                                                  const float* __restrict__ MU,
                                                  const float* __restrict__ SPREAD,
                                                  const float* __restrict__ SE,
                                                  double* __restrict__ NLLP) {
    __shared__ double red[256];
    int tid = threadIdx.x;
    int bq = blockIdx.x * 256 + tid;
    float se = SE[0];
    float sp = SPREAD[bq];
    float qs = 0.0f;
    const float4* y4 = (const float4*)(YQ + bq * 64);
    const float4* m4 = (const float4*)(MU + bq * 64);
#pragma unroll
    for (int t = 0; t < 16; ++t) {
        float4 y = y4[t], m = m4[t];
        float dx = y.x - m.x, dy = y.y - m.y, dz = y.z - m.z, dw = y.w - m.w;
        qs += dx * dx + dy * dy + dz * dz + dw * dw;
    }
    float val = 64.0f * (logf(sp) + logf(se)) + qs / (sp * se);
    red[tid] = (double)val;
    __syncthreads();
    for (int s = 128; s > 0; s >>= 1) {
        if (tid < s) red[tid] += red[tid + s];
        __syncthreads();
    }
    if (tid == 0) NLLP[blockIdx.x] = red[0] * (1.0 / 65536.0);
}

__global__ __launch_bounds__(256) void k_nll_final(const double* __restrict__ NLLP,
                                                   float* __restrict__ out) {
    __shared__ double red[256];
    int tid = threadIdx.x;
    red[tid] = NLLP[tid];
    __syncthreads();
    for (int s = 128; s > 0; s >>= 1) {
        if (tid < s) red[tid] += red[tid + s];
        __syncthreads();
    }
    if (tid == 0) out[NLL_IDX] = (float)red[0];
}

// ---------------------------------------------------------------------------
// K7 (runs LAST): stream sig = spread*sig_eps on the diagonal, zeros elsewhere.
//     Fully overwrites the sig region (which earlier kernels used as scratch).
// ---------------------------------------------------------------------------
__global__ __launch_bounds__(256) void k_sig(const float* __restrict__ SPREAD,
                                             const float* __restrict__ SE,
                                             float* __restrict__ out) {
    __shared__ float sv_s;
    int bq = blockIdx.x, tid = threadIdx.x;
    if (tid == 0) sv_s = SPREAD[bq] * SE[0];
    __syncthreads();
    float sv = sv_s;
    float* base = out + (size_t)MU_SIZE + (size_t)bq * 4096;
    int i = tid >> 2;                 // row within 64x64
    int jb = (tid & 3) << 4;          // 16-col segment start
    int d = i - jb;                   // diag offset within this thread's 16 floats
    float vals[16];
#pragma unroll
    for (int t = 0; t < 16; ++t) vals[t] = (t == d) ? sv : 0.0f;
    float4* p = (float4*)(base + tid * 16);
    p[0] = make_float4(vals[0], vals[1], vals[2], vals[3]);
    p[1] = make_float4(vals[4], vals[5], vals[6], vals[7]);
    p[2] = make_float4(vals[8], vals[9], vals[10], vals[11]);
    p[3] = make_float4(vals[12], vals[13], vals[14], vals[15]);
}

// ---------------------------------------------------------------------------
extern "C" void kernel_launch(void* const* d_in, const int* in_sizes, int n_in,
                              void* d_out, int out_size, void* d_ws, size_t ws_size,
                              hipStream_t stream) {
    const float* PHI_S = (const float*)d_in[0];
    const float* Y_S   = (const float*)d_in[1];
    const float* PHI_Q = (const float*)d_in[2];
    const float* Y_Q   = (const float*)d_in[3];
    const float* MP    = (const float*)d_in[4];
    const float* AP    = (const float*)d_in[5];
    const float* SE    = (const float*)d_in[6];
    float* out = (float*)d_out;

    // Big scratch lives inside the sig region of d_out (dead before k_sig runs last).
    double* scratch = (double*)(out + MU_SIZE);      // byte offset 16 MB, 8-aligned
    double* G    = scratch;                           // 8,388,608 doubles
    double* LT   = G + 8388608;                       // 8,388,608
    double* RHS  = LT + 8388608;                      // 2,097,152 (becomes m)
    double* Spd  = RHS + 2097152;                     // 65,536
    double* MPN  = Spd + 65536;                       // 16,384
    double* INVD = MPN + 16384;                       // 32,768
    // Small persistent scratch (survives until k_sig) in d_ws: 258 KB total.
    float*  SPREAD = (float*)d_ws;                    // 65,536 floats
    double* NLLP   = (double*)((char*)d_ws + 65536 * 4); // 256 doubles

    k_prior_sp <<<256, 256, 0, stream>>>(AP, Spd);
    k_prior_mpn<<<256, 64, 0, stream>>>(Spd, MP, MPN);
    k_build_G  <<<dim3(B_T, 10), 256, 0, stream>>>(PHI_S, Spd, G);
    k_build_rhs<<<dim3(B_T, 4), 256, 0, stream>>>(PHI_S, Y_S, MPN, RHS);
    k_chol     <<<B_T, 256, 0, stream>>>(G, LT, INVD);
    k_solve_m  <<<dim3(B_T, 2), 256, 0, stream>>>(LT, INVD, RHS);
    k_spread   <<<dim3(B_T, 8), 256, 0, stream>>>(PHI_Q, LT, INVD, SPREAD);
    k_mu       <<<dim3(B_T, 8), 256, 0, stream>>>(PHI_Q, RHS, out);
    k_nll_part <<<256, 256, 0, stream>>>(Y_Q, out, SPREAD, SE, NLLP);
    k_nll_final<<<1, 256, 0, stream>>>(NLLP, out);
    k_sig      <<<65536, 256, 0, stream>>>(SPREAD, SE, out);   // LAST: overwrites scratch
}

// Round 2
// 2502.298 us; speedup vs baseline: 2.0781x; 2.0781x over previous
//
#include <hip/hip_runtime.h>
#include <math.h>

#define B_T   128
#define NS    128
#define NQ    512
#define DIN   256
#define DOUT  64

#define MU_SIZE  (B_T*NQ*DOUT)            // 4,194,304 floats
#define SIG_SIZE (B_T*NQ*DOUT*DOUT)       // 268,435,456 floats
#define NLL_IDX  (MU_SIZE + SIG_SIZE)     // 272,629,760

// ---------------------------------------------------------------------------
// K0a: Sp = A @ A^T  (fp64 accumulate), alpha = 1
// ---------------------------------------------------------------------------
__global__ __launch_bounds__(256) void k_prior_sp(const float* __restrict__ A,
                                                  double* __restrict__ Sp) {
    __shared__ float Ai[16][260];
    __shared__ float Aj[16][260];
    int bi = blockIdx.x;
    int i0 = (bi >> 4) << 4;
    int j0 = (bi & 15) << 4;
    int tid = threadIdx.x;
    for (int idx = tid; idx < 16 * 256; idx += 256) {
        int r = idx >> 8, c = idx & 255;
        Ai[r][c] = A[(i0 + r) * 256 + c];
        Aj[r][c] = A[(j0 + r) * 256 + c];
    }
    __syncthreads();
    int r = tid >> 4, c = tid & 15;
    double acc = 0.0;
    for (int k = 0; k < 256; ++k)
        acc += (double)Ai[r][k] * (double)Aj[c][k];
    Sp[(i0 + r) * 256 + (j0 + c)] = acc;
}

// ---------------------------------------------------------------------------
// K0b: MPN = Sp @ m_prior
// ---------------------------------------------------------------------------
__global__ __launch_bounds__(64) void k_prior_mpn(const double* __restrict__ Sp,
                                                  const float* __restrict__ MP,
                                                  double* __restrict__ MPN) {
    int i = blockIdx.x, k = threadIdx.x;
    double acc = 0.0;
    for (int t = 0; t < 256; ++t)
        acc += Sp[i * 256 + t] * (double)MP[t * 64 + k];
    MPN[i * 64 + k] = acc;
}

// ---------------------------------------------------------------------------
// K1: G_b = Phi_s^T Phi_s + Sp   (lower-triangle 64x64 tiles only, fp64)
// ---------------------------------------------------------------------------
__global__ __launch_bounds__(256) void k_build_G(const float* __restrict__ PHI,
                                                 const double* __restrict__ Sp,
                                                 double* __restrict__ G) {
    __shared__ float As[128][64];
    __shared__ float Bs[128][64];
    int b = blockIdx.x;
    int by = blockIdx.y;
    int ti = 0;
    while (((ti + 1) * (ti + 2)) / 2 <= by) ti++;
    int tj = by - (ti * (ti + 1)) / 2;
    int i0 = ti * 64, j0 = tj * 64;
    int tid = threadIdx.x;
    const float* Pb = PHI + b * (NS * DIN);
    for (int idx = tid; idx < 128 * 64; idx += 256) {
        int n = idx >> 6, c = idx & 63;
        As[n][c] = Pb[n * 256 + i0 + c];
        Bs[n][c] = Pb[n * 256 + j0 + c];
    }
    __syncthreads();
    int tx = tid & 15, ty = tid >> 4;
    double acc[4][4];
#pragma unroll
    for (int r = 0; r < 4; ++r)
#pragma unroll
        for (int s = 0; s < 4; ++s) acc[r][s] = 0.0;
    for (int n = 0; n < 128; ++n) {
        float a0 = As[n][4 * ty + 0], a1 = As[n][4 * ty + 1];
        float a2 = As[n][4 * ty + 2], a3 = As[n][4 * ty + 3];
        float b0 = Bs[n][4 * tx + 0], b1 = Bs[n][4 * tx + 1];
        float b2 = Bs[n][4 * tx + 2], b3 = Bs[n][4 * tx + 3];
        acc[0][0] += (double)a0 * b0; acc[0][1] += (double)a0 * b1;
        acc[0][2] += (double)a0 * b2; acc[0][3] += (double)a0 * b3;
        acc[1][0] += (double)a1 * b0; acc[1][1] += (double)a1 * b1;
        acc[1][2] += (double)a1 * b2; acc[1][3] += (double)a1 * b3;
        acc[2][0] += (double)a2 * b0; acc[2][1] += (double)a2 * b1;
        acc[2][2] += (double)a2 * b2; acc[2][3] += (double)a2 * b3;
        acc[3][0] += (double)a3 * b0; acc[3][1] += (double)a3 * b1;
        acc[3][2] += (double)a3 * b2; acc[3][3] += (double)a3 * b3;
    }
    double* Gb = G + b * 65536;
#pragma unroll
    for (int r = 0; r < 4; ++r) {
        int i = i0 + 4 * ty + r;
#pragma unroll
        for (int s = 0; s < 4; ++s) {
            int j = j0 + 4 * tx + s;
            Gb[i * 256 + j] = acc[r][s] + Sp[i * 256 + j];
        }
    }
}

// ---------------------------------------------------------------------------
// K2: RHS_b = Phi_s^T Y_s + MPN  (fp64)
// ---------------------------------------------------------------------------
__global__ __launch_bounds__(256) void k_build_rhs(const float* __restrict__ PHI,
                                                   const float* __restrict__ Y,
                                                   const double* __restrict__ MPN,
                                                   double* __restrict__ RHS) {
    __shared__ float As[128][64];
    __shared__ float Ys[128][64];
    int b = blockIdx.x, i0 = blockIdx.y * 64, tid = threadIdx.x;
    const float* Pb = PHI + b * (NS * DIN);
    const float* Yb = Y + b * (NS * DOUT);
    for (int idx = tid; idx < 128 * 64; idx += 256) {
        int n = idx >> 6, c = idx & 63;
        As[n][c] = Pb[n * 256 + i0 + c];
        Ys[n][c] = Yb[n * 64 + c];
    }
    __syncthreads();
    int tx = tid & 15, ty = tid >> 4;
    double acc[4][4];
#pragma unroll
    for (int r = 0; r < 4; ++r)
#pragma unroll
        for (int s = 0; s < 4; ++s) acc[r][s] = 0.0;
    for (int n = 0; n < 128; ++n) {
        float a0 = As[n][4 * ty + 0], a1 = As[n][4 * ty + 1];
        float a2 = As[n][4 * ty + 2], a3 = As[n][4 * ty + 3];
        float y0 = Ys[n][4 * tx + 0], y1 = Ys[n][4 * tx + 1];
        float y2 = Ys[n][4 * tx + 2], y3 = Ys[n][4 * tx + 3];
        acc[0][0] += (double)a0 * y0; acc[0][1] += (double)a0 * y1;
        acc[0][2] += (double)a0 * y2; acc[0][3] += (double)a0 * y3;
        acc[1][0] += (double)a1 * y0; acc[1][1] += (double)a1 * y1;
        acc[1][2] += (double)a1 * y2; acc[1][3] += (double)a1 * y3;
        acc[2][0] += (double)a2 * y0; acc[2][1] += (double)a2 * y1;
        acc[2][2] += (double)a2 * y2; acc[2][3] += (double)a2 * y3;
        acc[3][0] += (double)a3 * y0; acc[3][1] += (double)a3 * y1;
        acc[3][2] += (double)a3 * y2; acc[3][3] += (double)a3 * y3;
    }
    double* Rb = RHS + b * 16384;
#pragma unroll
    for (int r = 0; r < 4; ++r) {
        int i = i0 + 4 * ty + r;
#pragma unroll
        for (int s = 0; s < 4; ++s) {
            int kc = 4 * tx + s;
            Rb[i * 64 + kc] = acc[r][s] + MPN[i * 64 + kc];
        }
    }
}

// ---------------------------------------------------------------------------
// K3: blocked Cholesky (NB=8) of G_b (lower, fp64), in-place.
//     Writes transposed factor LT[k*256+i] = L[i][k] (i>=k) and INVD[k]=1/L[k][k].
// ---------------------------------------------------------------------------
__global__ __launch_bounds__(256) void k_chol(double* __restrict__ G,
                                              double* __restrict__ LT,
                                              double* __restrict__ INVD) {
    __shared__ double P[8][256];
    int b = blockIdx.x, tid = threadIdx.x;
    double* Gb = G + b * 65536;
    double* LTb = LT + b * 65536;
    for (int k0 = 0; k0 < 256; k0 += 8) {
#pragma unroll
        for (int p = 0; p < 8; ++p) P[p][tid] = Gb[tid * 256 + k0 + p];
        __syncthreads();
        for (int p = 0; p < 8; ++p) {
            int k = k0 + p;
            if (tid >= k) {
                double v = P[p][tid];
                for (int p2 = 0; p2 < p; ++p2) v -= P[p2][tid] * P[p2][k];
                P[p][tid] = v;
            }
            __syncthreads();
            double d = sqrt(fmax(P[p][k], 1e-300));
            double inv = 1.0 / d;
            if (tid > k) P[p][tid] *= inv;
            else if (tid == k) { P[p][tid] = d; INVD[b * 256 + k] = inv; }
            __syncthreads();
        }
#pragma unroll
        for (int p = 0; p < 8; ++p) {
            int k = k0 + p;
            if (tid >= k) LTb[k * 256 + tid] = P[p][tid];
        }
        int ty = tid >> 4, tx = tid & 15;
        for (int i = k0 + 8 + ty; i < 256; i += 16) {
            double pi[8];
#pragma unroll
            for (int p = 0; p < 8; ++p) pi[p] = P[p][i];
            for (int j = k0 + 8 + tx; j <= i; j += 16) {
                double g = Gb[i * 256 + j];
#pragma unroll
                for (int p = 0; p < 8; ++p) g -= pi[p] * P[p][j];
                Gb[i * 256 + j] = g;
            }
        }
        __syncthreads();
    }
}

// ---------------------------------------------------------------------------
// K3b: blocked triangular inversion  Tinv = L^{-1}  (fp64), per-task block.
//      Writes TI[i*256+k] (full square, zeros above diag) and fp32 copy TIF.
// ---------------------------------------------------------------------------
__global__ __launch_bounds__(256) void k_trinv(const double* __restrict__ LT,
                                               double* __restrict__ TI,
                                               float* __restrict__ TIF) {
    __shared__ double SHD[8192];   // 64 KB: 8 diag blocks, SHD[g*1024+k*32+i]=L[32g+i][32g+k]
    int b = blockIdx.x, tid = threadIdx.x;
    const double* LTb = LT + b * 65536;
    double* TIb = TI + b * 65536;
    float* TIFb = TIF + b * 65536;
    // phase 0: zero strictly-upper (k > i), stage diagonal blocks
    for (int idx = tid; idx < 65536; idx += 256) {
        int i = idx >> 8, k = idx & 255;
        if (k > i) { TIb[idx] = 0.0; TIFb[idx] = 0.0f; }
    }
    for (int idx = tid; idx < 8192; idx += 256) {
        int g = idx >> 10, rem = idx & 1023, k = rem >> 5, i = rem & 31;
        SHD[idx] = LTb[(32 * g + k) * 256 + 32 * g + i];
    }
    __syncthreads();
    // phase 1: invert 8 diagonal 32x32 blocks; group g=tid>>5 handles block g,
    // lane j=tid&31 computes column j of the inverse by forward substitution.
    {
        int g = tid >> 5, j = tid & 31;
        const double* D = SHD + g * 1024;       // D[k*32+i] = L[i][k]
        double x[32];
#pragma unroll
        for (int i = 0; i < 32; ++i) {
            double s = (i == j) ? 1.0 : 0.0;
#pragma unroll
            for (int k = 0; k < i; ++k) {
                double lv = D[k * 32 + i];
                s -= (k >= j) ? lv * x[k] : 0.0;
            }
            double inv = 1.0 / D[i * 32 + i];
            x[i] = (i >= j) ? s * inv : 0.0;
        }
#pragma unroll
        for (int i = 0; i < 32; ++i) {
            int gi = 32 * g + i, gj = 32 * g + j;
            TIb[gi * 256 + gj] = x[i];
            TIFb[gi * 256 + gj] = (float)x[i];
        }
    }
    __syncthreads();
    // phase 2: off-diagonal blocks, I ascending:
    //   Tinv[I][J] = -DIinv_I * (sum_{K=J}^{I-1} L[I][K] * Tinv[K][J])
    double* Bsh = SHD;   // reuse 8 KB of SHD as 32x32 staging
    int j = tid & 31, ig = tid >> 5;    // rows i = ig*4 + r
    for (int I = 1; I < 8; ++I) {
        for (int J = I - 1; J >= 0; --J) {
            double acc[4] = {0.0, 0.0, 0.0, 0.0};
            for (int K = J; K < I; ++K) {
                for (int kk = 0; kk < 32; ++kk) {
                    double tv = TIb[(32 * K + kk) * 256 + 32 * J + j];
#pragma unroll
                    for (int r = 0; r < 4; ++r) {
                        double lv = LTb[(32 * K + kk) * 256 + 32 * I + ig * 4 + r];
                        acc[r] += lv * tv;
                    }
                }
            }
            __syncthreads();
#pragma unroll
            for (int r = 0; r < 4; ++r) Bsh[(ig * 4 + r) * 32 + j] = acc[r];
            __syncthreads();
            double c[4] = {0.0, 0.0, 0.0, 0.0};
            for (int k = 0; k < 32; ++k) {
                double bv = Bsh[k * 32 + j];
#pragma unroll
                for (int r = 0; r < 4; ++r) {
                    double dv = TIb[(32 * I + ig * 4 + r) * 256 + 32 * I + k];
                    c[r] -= dv * bv;
                }
            }
#pragma unroll
            for (int r = 0; r < 4; ++r) {
                int gi = 32 * I + ig * 4 + r, gj = 32 * J + j;
                TIb[gi * 256 + gj] = c[r];
                TIFb[gi * 256 + gj] = (float)c[r];
            }
        }
        __syncthreads();
    }
}

// ---------------------------------------------------------------------------
// K4a: Z = Tinv @ RHS  (fp64 tiled GEMM, triangular k-skip)
// ---------------------------------------------------------------------------
__global__ __launch_bounds__(256) void k_gemm_Z(const double* __restrict__ TI,
                                                const double* __restrict__ RHS,
                                                double* __restrict__ Z) {
    __shared__ double As[32][64];
    __shared__ double Bs[64][64];
    int b = blockIdx.x, i0 = blockIdx.y * 32;
    int tid = threadIdx.x, c = tid & 63, rg = tid >> 6;
    const double* TIb = TI + b * 65536;
    const double* Rb = RHS + b * 16384;
    double* Zb = Z + b * 16384;
    double acc[8] = {};
    for (int k0 = 0; k0 <= i0; k0 += 64) {
        for (int idx = tid; idx < 2048; idx += 256) {
            int r = idx >> 6, kk = idx & 63;
            As[r][kk] = TIb[(i0 + r) * 256 + k0 + kk];
        }
        for (int idx = tid; idx < 4096; idx += 256) {
            int kk = idx >> 6, cc = idx & 63;
            Bs[kk][cc] = Rb[(k0 + kk) * 64 + cc];
        }
        __syncthreads();
        for (int kk = 0; kk < 64; ++kk) {
            double bv = Bs[kk][c];
#pragma unroll
            for (int r = 0; r < 8; ++r)
                acc[r] += As[rg * 8 + r][kk] * bv;
        }
        __syncthreads();
    }
#pragma unroll
    for (int r = 0; r < 8; ++r)
        Zb[(i0 + rg * 8 + r) * 64 + c] = acc[r];
}

// ---------------------------------------------------------------------------
// K4b: M = Tinv^T @ Z  (fp64 tiled GEMM, triangular k-skip), M -> RHS buffer
// ---------------------------------------------------------------------------
__global__ __launch_bounds__(256) void k_gemm_M(const double* __restrict__ TI,
                                                const double* __restrict__ Z,
                                                double* __restrict__ M) {
    __shared__ double As[64][32];   // As[kk][ri] = TI[(k0+kk)*256 + i0+ri]
    __shared__ double Bs[64][64];
    int b = blockIdx.x, i0 = blockIdx.y * 32;
    int tid = threadIdx.x, c = tid & 63, rg = tid >> 6;
    const double* TIb = TI + b * 65536;
    const double* Zb = Z + b * 16384;
    double* Mb = M + b * 16384;
    double acc[8] = {};
    for (int k0 = (i0 >> 6) << 6; k0 < 256; k0 += 64) {
        for (int idx = tid; idx < 2048; idx += 256) {
            int kk = idx >> 5, ri = idx & 31;
            As[kk][ri] = TIb[(k0 + kk) * 256 + i0 + ri];
        }
        for (int idx = tid; idx < 4096; idx += 256) {
            int kk = idx >> 6, cc = idx & 63;
            Bs[kk][cc] = Zb[(k0 + kk) * 64 + cc];
        }
        __syncthreads();
        for (int kk = 0; kk < 64; ++kk) {
            double bv = Bs[kk][c];
#pragma unroll
            for (int r = 0; r < 8; ++r)
                acc[r] += As[kk][rg * 8 + r] * bv;
        }
        __syncthreads();
    }
#pragma unroll
    for (int r = 0; r < 8; ++r)
        Mb[(i0 + rg * 8 + r) * 64 + c] = acc[r];
}

// ---------------------------------------------------------------------------
// K5a: W = PhiQ @ TinvF^T, PSUM[b][I][q] = sum_{i in I-tile} W[q][i]^2  (fp32)
// ---------------------------------------------------------------------------
__global__ __launch_bounds__(256) void k_spread_gemm(const float* __restrict__ PHIQ,
                                                     const float* __restrict__ TIF,
                                                     float* __restrict__ PSUM) {
    __shared__ float Qs[64][65];   // [q][k]
    __shared__ float Ts[64][65];   // [k][i]
    int b = blockIdx.x, q0 = blockIdx.y * 64, I = blockIdx.z, i0 = I * 64;
    int tid = threadIdx.x, tx = tid & 15, ty = tid >> 4;
    const float* Qb = PHIQ + b * (NQ * DIN) + q0 * DIN;
    const float* Tb = TIF + b * 65536;
    float acc[4][4];
#pragma unroll
    for (int r = 0; r < 4; ++r)
#pragma unroll
        for (int s = 0; s < 4; ++s) acc[r][s] = 0.0f;
    for (int k0 = 0; k0 <= i0; k0 += 64) {
        for (int idx = tid; idx < 4096; idx += 256) {
            int r = idx >> 6, c = idx & 63;
            Qs[r][c] = Qb[r * 256 + k0 + c];
            Ts[c][r] = Tb[(i0 + r) * 256 + k0 + c];
        }
        __syncthreads();
        for (int kk = 0; kk < 64; ++kk) {
            float a0 = Qs[4 * ty + 0][kk], a1 = Qs[4 * ty + 1][kk];
            float a2 = Qs[4 * ty + 2][kk], a3 = Qs[4 * ty + 3][kk];
            float b0 = Ts[kk][4 * tx + 0], b1 = Ts[kk][4 * tx + 1];
            float b2 = Ts[kk][4 * tx + 2], b3 = Ts[kk][4 * tx + 3];
            acc[0][0] += a0 * b0; acc[0][1] += a0 * b1; acc[0][2] += a0 * b2; acc[0][3] += a0 * b3;
            acc[1][0] += a1 * b0; acc[1][1] += a1 * b1; acc[1][2] += a1 * b2; acc[1][3] += a1 * b3;
            acc[2][0] += a2 * b0; acc[2][1] += a2 * b1; acc[2][2] += a2 * b2; acc[2][3] += a2 * b3;
            acc[3][0] += a3 * b0; acc[3][1] += a3 * b1; acc[3][2] += a3 * b2; acc[3][3] += a3 * b3;
        }
        __syncthreads();
    }
#pragma unroll
    for (int r = 0; r < 4; ++r) {
        float p = acc[r][0] * acc[r][0] + acc[r][1] * acc[r][1]
                + acc[r][2] * acc[r][2] + acc[r][3] * acc[r][3];
        p += __shfl_down(p, 8, 16);
        p += __shfl_down(p, 4, 16);
        p += __shfl_down(p, 2, 16);
        p += __shfl_down(p, 1, 16);
        if (tx == 0) PSUM[(size_t)(b * 4 + I) * 512 + q0 + 4 * ty + r] = p;
    }
}

// ---------------------------------------------------------------------------
// K5b: SPREAD = 1 + sum_I PSUM
// ---------------------------------------------------------------------------
__global__ __launch_bounds__(256) void k_spread_combine(const float* __restrict__ PSUM,
                                                        float* __restrict__ SPREAD) {
    int b = blockIdx.x;
    for (int q = threadIdx.x; q < 512; q += 256) {
        float s = 1.0f;
#pragma unroll
        for (int I = 0; I < 4; ++I) s += PSUM[(size_t)(b * 4 + I) * 512 + q];
        SPREAD[b * 512 + q] = s;
    }
}

// ---------------------------------------------------------------------------
// K6: mu = Phi_q @ m  (fp32 GEMM, m cast from fp64)
// ---------------------------------------------------------------------------
__global__ __launch_bounds__(256) void k_mu(const float* __restrict__ PHIQ,
                                            const double* __restrict__ M,
                                            float* __restrict__ MU) {
    __shared__ float Qs[64][65];
    __shared__ float Ms[64][64];
    int b = blockIdx.x, q0 = blockIdx.y * 64, tid = threadIdx.x;
    int tx = tid & 15, ty = tid >> 4;
    const float* Qb = PHIQ + b * (NQ * DIN) + q0 * DIN;
    const double* Mb = M + b * 16384;
    float acc[4][4];
#pragma unroll
    for (int r = 0; r < 4; ++r)
#pragma unroll
        for (int s = 0; s < 4; ++s) acc[r][s] = 0.0f;
    for (int c0 = 0; c0 < 256; c0 += 64) {
        for (int idx = tid; idx < 4096; idx += 256) {
            int r = idx >> 6, c = idx & 63;
            Qs[r][c] = Qb[r * 256 + c0 + c];
            Ms[r][c] = (float)Mb[(c0 + r) * 64 + c];
        }
        __syncthreads();
        for (int kk = 0; kk < 64; ++kk) {
            float a0 = Qs[4 * ty + 0][kk], a1 = Qs[4 * ty + 1][kk];
            float a2 = Qs[4 * ty + 2][kk], a3 = Qs[4 * ty + 3][kk];
            float b0 = Ms[kk][4 * tx + 0], b1 = Ms[kk][4 * tx + 1];
            float b2 = Ms[kk][4 * tx + 2], b3 = Ms[kk][4 * tx + 3];
            acc[0][0] += a0 * b0; acc[0][1] += a0 * b1; acc[0][2] += a0 * b2; acc[0][3] += a0 * b3;
            acc[1][0] += a1 * b0; acc[1][1] += a1 * b1; acc[1][2] += a1 * b2; acc[1][3] += a1 * b3;
            acc[2][0] += a2 * b0; acc[2][1] += a2 * b1; acc[2][2] += a2 * b2; acc[2][3] += a2 * b3;
            acc[3][0] += a3 * b0; acc[3][1] += a3 * b1; acc[3][2] += a3 * b2; acc[3][3] += a3 * b3;
        }
        __syncthreads();
    }
#pragma unroll
    for (int r = 0; r < 4; ++r) {
        float4 v = make_float4(acc[r][0], acc[r][1], acc[r][2], acc[r][3]);
        *(float4*)&MU[(b * NQ + q0 + 4 * ty + r) * 64 + 4 * tx] = v;
    }
}

// ---------------------------------------------------------------------------
// K8: nll partial sums
// ---------------------------------------------------------------------------
__global__ __launch_bounds__(256) void k_nll_part(const float* __restrict__ YQ,
                                                  const float* __restrict__ MU,
                                                  const float* __restrict__ SPREAD,
                                                  const float* __restrict__ SE,
                                                  double* __restrict__ NLLP) {
    __shared__ double red[256];
    int tid = threadIdx.x;
    int bq = blockIdx.x * 256 + tid;
    float se = SE[0];
    float sp = SPREAD[bq];
    float qs = 0.0f;
    const float4* y4 = (const float4*)(YQ + bq * 64);
    const float4* m4 = (const float4*)(MU + bq * 64);
#pragma unroll
    for (int t = 0; t < 16; ++t) {
        float4 y = y4[t], m = m4[t];
        float dx = y.x - m.x, dy = y.y - m.y, dz = y.z - m.z, dw = y.w - m.w;
        qs += dx * dx + dy * dy + dz * dz + dw * dw;
    }
    float val = 64.0f * (logf(sp) + logf(se)) + qs / (sp * se);
    red[tid] = (double)val;
    __syncthreads();
    for (int s = 128; s > 0; s >>= 1) {
        if (tid < s) red[tid] += red[tid + s];
        __syncthreads();
    }
    if (tid == 0) NLLP[blockIdx.x] = red[0] * (1.0 / 65536.0);
}

__global__ __launch_bounds__(256) void k_nll_final(const double* __restrict__ NLLP,
                                                   float* __restrict__ out) {
    __shared__ double red[256];
    int tid = threadIdx.x;
    red[tid] = NLLP[tid];
    __syncthreads();
    for (int s = 128; s > 0; s >>= 1) {
        if (tid < s) red[tid] += red[tid + s];
        __syncthreads();
    }
    if (tid == 0) out[NLL_IDX] = (float)red[0];
}

// ---------------------------------------------------------------------------
// K7 (runs LAST): stream sig; fully overwrites scratch inside d_out sig region.
// ---------------------------------------------------------------------------
__global__ __launch_bounds__(256) void k_sig(const float* __restrict__ SPREAD,
                                             const float* __restrict__ SE,
                                             float* __restrict__ out) {
    __shared__ float sv_s;
    int bq = blockIdx.x, tid = threadIdx.x;
    if (tid == 0) sv_s = SPREAD[bq] * SE[0];
    __syncthreads();
    float sv = sv_s;
    float* base = out + (size_t)MU_SIZE + (size_t)bq * 4096;
    int i = tid >> 2;
    int jb = (tid & 3) << 4;
    int d = i - jb;
    float vals[16];
#pragma unroll
    for (int t = 0; t < 16; ++t) vals[t] = (t == d) ? sv : 0.0f;
    float4* p = (float4*)(base + tid * 16);
    p[0] = make_float4(vals[0], vals[1], vals[2], vals[3]);
    p[1] = make_float4(vals[4], vals[5], vals[6], vals[7]);
    p[2] = make_float4(vals[8], vals[9], vals[10], vals[11]);
    p[3] = make_float4(vals[12], vals[13], vals[14], vals[15]);
}

// ---------------------------------------------------------------------------
extern "C" void kernel_launch(void* const* d_in, const int* in_sizes, int n_in,
                              void* d_out, int out_size, void* d_ws, size_t ws_size,
                              hipStream_t stream) {
    const float* PHI_S = (const float*)d_in[0];
    const float* Y_S   = (const float*)d_in[1];
    const float* PHI_Q = (const float*)d_in[2];
    const float* Y_Q   = (const float*)d_in[3];
    const float* MP    = (const float*)d_in[4];
    const float* AP    = (const float*)d_in[5];
    const float* SE    = (const float*)d_in[6];
    float* out = (float*)d_out;

    // Big scratch inside sig region of d_out (dead before k_sig runs last).
    double* scratch = (double*)(out + MU_SIZE);
    double* G    = scratch;                    // 8,388,608 dbl (64 MB)
    double* LT   = G + 8388608;                // 8,388,608 dbl
    double* RHS  = LT + 8388608;               // 2,097,152 dbl (-> becomes M)
    double* Z    = RHS + 2097152;              // 2,097,152 dbl
    double* TI   = Z + 2097152;                // 8,388,608 dbl
    double* Spd  = TI + 8388608;               // 65,536 dbl
    double* MPN  = Spd + 65536;                // 16,384 dbl
    double* INVD = MPN + 16384;                // 32,768 dbl
    float*  TIF  = (float*)(INVD + 32768);     // 8,388,608 f32 (32 MB)
    float*  PSUM = TIF + 8388608;              // 262,144 f32 (1 MB)
    // Small persistent scratch (survives until k_sig) in d_ws.
    float*  SPREAD = (float*)d_ws;                       // 65,536 f32
    double* NLLP   = (double*)((char*)d_ws + 65536 * 4); // 256 dbl

    k_prior_sp      <<<256, 256, 0, stream>>>(AP, Spd);
    k_prior_mpn     <<<256, 64, 0, stream>>>(Spd, MP, MPN);
    k_build_G       <<<dim3(B_T, 10), 256, 0, stream>>>(PHI_S, Spd, G);
    k_build_rhs     <<<dim3(B_T, 4), 256, 0, stream>>>(PHI_S, Y_S, MPN, RHS);
    k_chol          <<<B_T, 256, 0, stream>>>(G, LT, INVD);
    k_trinv         <<<B_T, 256, 0, stream>>>(LT, TI, TIF);
    k_gemm_Z        <<<dim3(B_T, 8), 256, 0, stream>>>(TI, RHS, Z);
    k_gemm_M        <<<dim3(B_T, 8), 256, 0, stream>>>(TI, Z, RHS);
    k_spread_gemm   <<<dim3(B_T, 8, 4), 256, 0, stream>>>(PHI_Q, TIF, PSUM);
    k_spread_combine<<<B_T, 256, 0, stream>>>(PSUM, SPREAD);
    k_mu            <<<dim3(B_T, 8), 256, 0, stream>>>(PHI_Q, RHS, out);
    k_nll_part      <<<256, 256, 0, stream>>>(Y_Q, out, SPREAD, SE, NLLP);
    k_nll_final     <<<1, 256, 0, stream>>>(NLLP, out);
    k_sig           <<<65536, 256, 0, stream>>>(SPREAD, SE, out);   // LAST
}